// Round 1
// baseline (2736.270 us; speedup 1.0000x reference)
//
#include <hip/hip_runtime.h>

#define NB    1024
#define TSEQ  336
#define DIM   64
#define GATES 256
#define PRED  96

// shared-memory layout (float offsets)
#define OFF_WT0   0        // [2][16][4][256] = 32768 ; m=0: W_ih0, m=1: W_hh0 (component-major chunks)
#define OFF_WTFC  16384    // decoder overlay on W_hh0 region: [16][4][64] = 4096
#define OFF_BSUM0 32768    // 256
#define OFF_BSUM1 33024    // 256
#define OFF_BFC   33280    // 64
#define OFF_XBUF  33344    // [4][64]
#define OFF_H0    33600    // [4][64]
#define OFF_H1    33856    // [4][64]
#define OFF_DBUF  34112    // [4][64]
#define OFF_PRE   34368    // [4][256]
#define SMEM_FLOATS 35392
#define SMEM_BYTES  (SMEM_FLOATS * 4)

__device__ __forceinline__ float sigm(float v)  { return 1.0f / (1.0f + __expf(-v)); }
__device__ __forceinline__ float tanh_(float v) { return 1.0f - 2.0f / (__expf(2.0f * v) + 1.0f); }

__device__ __forceinline__ void fma4(float& acc, const float4 xv,
                                     float w0, float w1, float w2, float w3) {
    acc = fmaf(xv.x, w0, acc); acc = fmaf(xv.y, w1, acc);
    acc = fmaf(xv.z, w2, acc); acc = fmaf(xv.w, w3, acc);
}
__device__ __forceinline__ void fma4v(float& acc, const float4 xv, const float4 w) {
    acc = fmaf(xv.x, w.x, acc); acc = fmaf(xv.y, w.y, acc);
    acc = fmaf(xv.z, w.z, acc); acc = fmaf(xv.w, w.w, acc);
}

extern "C" __global__ void __launch_bounds__(256, 1)
rnn_fused(const float* __restrict__ x,
          const float* __restrict__ Wih0, const float* __restrict__ Whh0,
          const float* __restrict__ bih0, const float* __restrict__ bhh0,
          const float* __restrict__ Wih1, const float* __restrict__ Whh1,
          const float* __restrict__ bih1, const float* __restrict__ bhh1,
          const float* __restrict__ Wfc,  const float* __restrict__ bfc,
          float* __restrict__ out)
{
    extern __shared__ float sm[];
    const int tid = threadIdx.x;
    const int bid = blockIdx.x;
    const int a   = tid >> 7;        // 0..1 : which pair of batch rows (wave-uniform)
    const int b   = tid & 127;
    const int g0  = b;               // gate rows g0 and g0+128
    const int g1  = b + 128;
    const int r_  = tid >> 6;        // 0..3 : staging / gate-combine role
    const int j_  = tid & 63;

    // --- stage layer-0 weights into LDS, component-major: WT[m][k4][c][g] = W[g][4*k4+c] ---
    for (int idx = tid; idx < 2 * GATES * DIM; idx += 256) {
        const int m   = idx >> 14;
        const int rem = idx & 16383;
        const int g   = rem >> 6, k = rem & 63;
        const float* src = m ? Whh0 : Wih0;
        sm[OFF_WT0 + m * 16384 + (k >> 2) * 1024 + (k & 3) * 256 + g] = src[rem];
    }
    if (tid < GATES) {
        sm[OFF_BSUM0 + tid] = bih0[tid] + bhh0[tid];
        sm[OFF_BSUM1 + tid] = bih1[tid] + bhh1[tid];
    }
    if (tid < DIM) sm[OFF_BFC + tid] = bfc[tid];
    sm[OFF_H0 + tid] = 0.0f;
    sm[OFF_H1 + tid] = 0.0f;

    // --- layer-1 weights live in registers: rows g0,g1 of W_ih1 / W_hh1 (256 VGPRs) ---
    float4 wi1a[16], wi1b[16], wh1a[16], wh1b[16];
#pragma unroll
    for (int k4 = 0; k4 < 16; ++k4) {
        wi1a[k4] = *reinterpret_cast<const float4*>(Wih1 + g0 * DIM + k4 * 4);
        wi1b[k4] = *reinterpret_cast<const float4*>(Wih1 + g1 * DIM + k4 * 4);
        wh1a[k4] = *reinterpret_cast<const float4*>(Whh1 + g0 * DIM + k4 * 4);
        wh1b[k4] = *reinterpret_cast<const float4*>(Whh1 + g1 * DIM + k4 * 4);
    }

    __syncthreads();

    const float bs0g0 = sm[OFF_BSUM0 + g0], bs0g1 = sm[OFF_BSUM0 + g1];
    const float bs1g0 = sm[OFF_BSUM1 + g0], bs1g1 = sm[OFF_BSUM1 + g1];

    const float4* xb4 = reinterpret_cast<const float4*>(sm + OFF_XBUF);
    const float4* h04 = reinterpret_cast<const float4*>(sm + OFF_H0);
    const float4* h14 = reinterpret_cast<const float4*>(sm + OFF_H1);
    float* pre = sm + OFF_PRE;

    const int row0 = bid * 4;
    const float* xsrc = x + (row0 + r_) * TSEQ * DIM + j_;

    float c0 = 0.0f, c1 = 0.0f;
    const int pa0 = (2 * a) * GATES, pa1 = (2 * a + 1) * GATES;

    // ===================== encoder: 336 fused 2-layer LSTM steps =====================
    for (int s = 0; s < TSEQ; ++s) {
        sm[OFF_XBUF + tid] = xsrc[s * DIM];       // xbuf[r_][j_]
        __syncthreads();

        // ---- layer 0: pre = x@Wih0^T + h0@Whh0^T + bsum0 ----
        float a00 = bs0g0, a01 = bs0g1, a10 = bs0g0, a11 = bs0g1;
#pragma unroll 4
        for (int k4 = 0; k4 < 16; ++k4) {
            const float4 xv0 = xb4[(2 * a) * 16 + k4];      // LDS broadcast
            const float4 xv1 = xb4[(2 * a + 1) * 16 + k4];
            const float* wp = sm + OFF_WT0 + k4 * 1024;
            const float wa0 = wp[g0], wa1 = wp[g0 + 256], wa2 = wp[g0 + 512], wa3 = wp[g0 + 768];
            const float wb0 = wp[g1], wb1 = wp[g1 + 256], wb2 = wp[g1 + 512], wb3 = wp[g1 + 768];
            fma4(a00, xv0, wa0, wa1, wa2, wa3); fma4(a01, xv0, wb0, wb1, wb2, wb3);
            fma4(a10, xv1, wa0, wa1, wa2, wa3); fma4(a11, xv1, wb0, wb1, wb2, wb3);
        }
#pragma unroll 4
        for (int k4 = 0; k4 < 16; ++k4) {
            const float4 hv0 = h04[(2 * a) * 16 + k4];
            const float4 hv1 = h04[(2 * a + 1) * 16 + k4];
            const float* wp = sm + OFF_WT0 + 16384 + k4 * 1024;
            const float wa0 = wp[g0], wa1 = wp[g0 + 256], wa2 = wp[g0 + 512], wa3 = wp[g0 + 768];
            const float wb0 = wp[g1], wb1 = wp[g1 + 256], wb2 = wp[g1 + 512], wb3 = wp[g1 + 768];
            fma4(a00, hv0, wa0, wa1, wa2, wa3); fma4(a01, hv0, wb0, wb1, wb2, wb3);
            fma4(a10, hv1, wa0, wa1, wa2, wa3); fma4(a11, hv1, wb0, wb1, wb2, wb3);
        }
        pre[pa0 + g0] = a00; pre[pa0 + g1] = a01;
        pre[pa1 + g0] = a10; pre[pa1 + g1] = a11;
        __syncthreads();

        {   // gate combine, thread owns (r_, j_)
            const float* pr = pre + r_ * GATES;
            const float ig = sigm(pr[j_]);
            const float fg = sigm(pr[64 + j_]);
            const float gg = tanh_(pr[128 + j_]);
            const float og = sigm(pr[192 + j_]);
            c0 = fmaf(fg, c0, ig * gg);
            sm[OFF_H0 + tid] = og * tanh_(c0);    // layer-0 h -> layer-1 input + recurrence
        }
        __syncthreads();

        // ---- layer 1: weights from registers ----
        float b00 = bs1g0, b01 = bs1g1, b10 = bs1g0, b11 = bs1g1;
#pragma unroll
        for (int k4 = 0; k4 < 16; ++k4) {
            const float4 xv0 = h04[(2 * a) * 16 + k4];
            const float4 xv1 = h04[(2 * a + 1) * 16 + k4];
            fma4v(b00, xv0, wi1a[k4]); fma4v(b01, xv0, wi1b[k4]);
            fma4v(b10, xv1, wi1a[k4]); fma4v(b11, xv1, wi1b[k4]);
        }
#pragma unroll
        for (int k4 = 0; k4 < 16; ++k4) {
            const float4 hv0 = h14[(2 * a) * 16 + k4];
            const float4 hv1 = h14[(2 * a + 1) * 16 + k4];
            fma4v(b00, hv0, wh1a[k4]); fma4v(b01, hv0, wh1b[k4]);
            fma4v(b10, hv1, wh1a[k4]); fma4v(b11, hv1, wh1b[k4]);
        }
        pre[pa0 + g0] = b00; pre[pa0 + g1] = b01;
        pre[pa1 + g0] = b10; pre[pa1 + g1] = b11;
        __syncthreads();

        {
            const float* pr = pre + r_ * GATES;
            const float ig = sigm(pr[j_]);
            const float fg = sigm(pr[64 + j_]);
            const float gg = tanh_(pr[128 + j_]);
            const float og = sigm(pr[192 + j_]);
            c1 = fmaf(fg, c1, ig * gg);
            sm[OFF_H1 + tid] = og * tanh_(c1);
        }
        __syncthreads();
    }

    // ===================== decoder setup =====================
    // overlay W_fc (component-major) on the dead W_hh0 region
    for (int idx = tid; idx < DIM * DIM; idx += 256) {
        const int jj = idx >> 6, k = idx & 63;
        sm[OFF_WTFC + (k >> 2) * 256 + (k & 3) * 64 + jj] = Wfc[idx];
    }
    sm[OFF_DBUF + tid] = sm[OFF_H1 + tid];        // carry = h2[:, -1, :]
    __syncthreads();

    const float bfc_j = sm[OFF_BFC + j_];
    float* outp = out + (row0 + r_) * PRED * DIM + j_;
    const float4* db4 = reinterpret_cast<const float4*>(sm + OFF_DBUF);

    // ===================== decoder: 96 autoregressive steps =====================
    for (int p = 0; p < PRED; ++p) {
        // ---- cell0 (zero state): pre = dbuf@Wih0^T + bsum0 ----
        float a00 = bs0g0, a01 = bs0g1, a10 = bs0g0, a11 = bs0g1;
#pragma unroll 4
        for (int k4 = 0; k4 < 16; ++k4) {
            const float4 xv0 = db4[(2 * a) * 16 + k4];
            const float4 xv1 = db4[(2 * a + 1) * 16 + k4];
            const float* wp = sm + OFF_WT0 + k4 * 1024;
            const float wa0 = wp[g0], wa1 = wp[g0 + 256], wa2 = wp[g0 + 512], wa3 = wp[g0 + 768];
            const float wb0 = wp[g1], wb1 = wp[g1 + 256], wb2 = wp[g1 + 512], wb3 = wp[g1 + 768];
            fma4(a00, xv0, wa0, wa1, wa2, wa3); fma4(a01, xv0, wb0, wb1, wb2, wb3);
            fma4(a10, xv1, wa0, wa1, wa2, wa3); fma4(a11, xv1, wb0, wb1, wb2, wb3);
        }
        pre[pa0 + g0] = a00; pre[pa0 + g1] = a01;
        pre[pa1 + g0] = a10; pre[pa1 + g1] = a11;
        __syncthreads();
        {   // zero-state gates: c = i*g, h = o*tanh(c)
            const float* pr = pre + r_ * GATES;
            const float ig = sigm(pr[j_]);
            const float gg = tanh_(pr[128 + j_]);
            const float og = sigm(pr[192 + j_]);
            sm[OFF_H0 + tid] = og * tanh_(ig * gg);
        }
        __syncthreads();

        // ---- cell1 (zero state), W_ih1 from registers ----
        float b00 = bs1g0, b01 = bs1g1, b10 = bs1g0, b11 = bs1g1;
#pragma unroll
        for (int k4 = 0; k4 < 16; ++k4) {
            const float4 xv0 = h04[(2 * a) * 16 + k4];
            const float4 xv1 = h04[(2 * a + 1) * 16 + k4];
            fma4v(b00, xv0, wi1a[k4]); fma4v(b01, xv0, wi1b[k4]);
            fma4v(b10, xv1, wi1a[k4]); fma4v(b11, xv1, wi1b[k4]);
        }
        pre[pa0 + g0] = b00; pre[pa0 + g1] = b01;
        pre[pa1 + g0] = b10; pre[pa1 + g1] = b11;
        __syncthreads();
        {
            const float* pr = pre + r_ * GATES;
            const float ig = sigm(pr[j_]);
            const float gg = tanh_(pr[128 + j_]);
            const float og = sigm(pr[192 + j_]);
            sm[OFF_H1 + tid] = og * tanh_(ig * gg);
        }
        __syncthreads();

        // ---- FC: pred[r][j] = b_fc[j] + sum_k h1[r][k] * W_fc[j][k] ----
        float acc = bfc_j;
#pragma unroll 4
        for (int k4 = 0; k4 < 16; ++k4) {
            const float4 hv = h14[r_ * 16 + k4];
            const float* wp = sm + OFF_WTFC + k4 * 256;
            acc = fmaf(hv.x, wp[j_],       acc);
            acc = fmaf(hv.y, wp[64 + j_],  acc);
            acc = fmaf(hv.z, wp[128 + j_], acc);
            acc = fmaf(hv.w, wp[192 + j_], acc);
        }
        outp[p * DIM] = acc;          // out[row, p, j] — coalesced
        sm[OFF_DBUF + tid] = acc;     // feedback carry
        __syncthreads();
    }
}

extern "C" void kernel_launch(void* const* d_in, const int* in_sizes, int n_in,
                              void* d_out, int out_size, void* d_ws, size_t ws_size,
                              hipStream_t stream) {
    const float* x    = (const float*)d_in[0];
    const float* Wih0 = (const float*)d_in[1];
    const float* Whh0 = (const float*)d_in[2];
    const float* bih0 = (const float*)d_in[3];
    const float* bhh0 = (const float*)d_in[4];
    const float* Wih1 = (const float*)d_in[5];
    const float* Whh1 = (const float*)d_in[6];
    const float* bih1 = (const float*)d_in[7];
    const float* bhh1 = (const float*)d_in[8];
    const float* Wfc  = (const float*)d_in[9];
    const float* bfc  = (const float*)d_in[10];
    float* out = (float*)d_out;

    // >64KB dynamic LDS opt-in (idempotent, host-side, graph-capture safe)
    (void)hipFuncSetAttribute(reinterpret_cast<const void*>(rnn_fused),
                              hipFuncAttributeMaxDynamicSharedMemorySize, SMEM_BYTES);

    hipLaunchKernelGGL(rnn_fused, dim3(256), dim3(256), SMEM_BYTES, stream,
                       x, Wih0, Whh0, bih0, bhh0, Wih1, Whh1, bih1, bhh1, Wfc, bfc, out);
}

// Round 2
// 2357.069 us; speedup vs baseline: 1.1609x; 1.1609x over previous
//
#include <hip/hip_runtime.h>

#define NB    1024
#define TSEQ  336
#define DIM   64
#define GATES 256
#define PRED  96
#define THREADS 512

// LDS layout (float offsets). Weight rows padded to stride 68
// (68 mod 32 == 4 -> ds_read_b128 lane windows cover all 32 banks per 8 lanes).
#define W0O   0        // W_ih0 [256][68] = 17408
#define W1O   17408    // W_hh0 [256][68]; decoder overlays W_fc [64][68]
#define PREO  34816    // partials [2][4][256] = 2048
#define H0O   36864    // [4][64]
#define H1O   37120    // [4][64]
#define DBO   37376    // [4][64] decoder feedback
#define BS0O  37632    // 256
#define BS1O  37888    // 256
#define BFCO  38144    // 64
#define SMF   38208
#define SMEM_BYTES (SMF * 4)

__device__ __forceinline__ float sigm(float v)  { return 1.0f / (1.0f + __expf(-v)); }
__device__ __forceinline__ float tanh_(float v) { return 1.0f - 2.0f / (__expf(2.0f * v) + 1.0f); }

__device__ __forceinline__ void fma4v(float& acc, const float4 xv, const float4 w) {
    acc = fmaf(xv.x, w.x, acc); acc = fmaf(xv.y, w.y, acc);
    acc = fmaf(xv.z, w.z, acc); acc = fmaf(xv.w, w.w, acc);
}

extern "C" __global__ void __launch_bounds__(THREADS, 2)
rnn_fused(const float* __restrict__ x,
          const float* __restrict__ Wih0, const float* __restrict__ Whh0,
          const float* __restrict__ bih0, const float* __restrict__ bhh0,
          const float* __restrict__ Wih1, const float* __restrict__ Whh1,
          const float* __restrict__ bih1, const float* __restrict__ bhh1,
          const float* __restrict__ Wfc,  const float* __restrict__ bfc,
          float* __restrict__ out)
{
    extern __shared__ float sm[];
    const int tid = threadIdx.x;
    const int bid = blockIdx.x;
    const int grp = tid >> 7;          // 0..3, wave-uniform
    const int a   = grp >> 1;          // row-pair: rows 2a, 2a+1
    const int q   = grp & 1;           // 0: ih-matrix partial, 1: hh-matrix partial
    const int gp  = tid & 127;
    const int g0  = gp, g1 = gp + 128; // the two gate rows this thread owns
    const int rr  = (tid & 255) >> 6;  // combine-phase row
    const int jj  = tid & 63;          // combine-phase hidden index

    // ---- stage layer-0 weights row-major stride-68 (coalesced global reads) ----
    for (int idx = tid; idx < GATES * DIM; idx += THREADS) {
        const int g = idx >> 6, k = idx & 63;
        sm[W0O + g * 68 + k] = Wih0[idx];
        sm[W1O + g * 68 + k] = Whh0[idx];
    }
    if (tid < GATES) {
        sm[BS0O + tid] = bih0[tid] + bhh0[tid];
        sm[BS1O + tid] = bih1[tid] + bhh1[tid];
    }
    if (tid < DIM) sm[BFCO + tid] = bfc[tid];
    if (tid < 256) { sm[H0O + tid] = 0.0f; sm[H1O + tid] = 0.0f; }

    // ---- layer-1 weights in registers: rows g0,g1 of (q ? W_hh1 : W_ih1) ----
    const float* Wsrc1 = q ? Whh1 : Wih1;
    float4 wra[16], wrb[16];
#pragma unroll
    for (int k4 = 0; k4 < 16; ++k4) {
        wra[k4] = *reinterpret_cast<const float4*>(Wsrc1 + g0 * DIM + k4 * 4);
        wrb[k4] = *reinterpret_cast<const float4*>(Wsrc1 + g1 * DIM + k4 * 4);
    }
    __syncthreads();

    const float i0a = q ? 0.0f : sm[BS0O + g0];
    const float i0b = q ? 0.0f : sm[BS0O + g1];
    const float i1a = q ? 0.0f : sm[BS1O + g0];
    const float i1b = q ? 0.0f : sm[BS1O + g1];

    const int row0 = bid * 4;
    const int r0 = 2 * a, r1 = 2 * a + 1;
    const float* xr0 = x + (size_t)(row0 + r0) * TSEQ * DIM;
    const float* xr1 = x + (size_t)(row0 + r1) * TSEQ * DIM;

    float* pre = sm + PREO;
    const int pw0 = q * 1024 + r0 * 256;   // partial-write bases
    const int pw1 = q * 1024 + r1 * 256;

    float c_state = 0.0f;   // c0 for tid<256 (r=rr,j=jj), c1 for tid>=256

    // ===================== encoder: 336 steps, 4 barriers each =====================
    for (int s = 0; s < TSEQ; ++s) {
        // ---- phase A: layer-0 partials ----
        float a00 = i0a, a01 = i0b, a10 = i0a, a11 = i0b;
        if (q == 0) {
            const float4* xp0 = reinterpret_cast<const float4*>(xr0 + s * DIM);
            const float4* xp1 = reinterpret_cast<const float4*>(xr1 + s * DIM);
#pragma unroll
            for (int k4 = 0; k4 < 16; ++k4) {
                const float4 w0 = *reinterpret_cast<const float4*>(sm + W0O + g0 * 68 + k4 * 4);
                const float4 w1 = *reinterpret_cast<const float4*>(sm + W0O + g1 * 68 + k4 * 4);
                const float4 xv0 = xp0[k4], xv1 = xp1[k4];   // uniform global, L1/L2 pipe
                fma4v(a00, xv0, w0); fma4v(a01, xv0, w1);
                fma4v(a10, xv1, w0); fma4v(a11, xv1, w1);
            }
        } else {
            const float4* hp0 = reinterpret_cast<const float4*>(sm + H0O + r0 * 64);
            const float4* hp1 = reinterpret_cast<const float4*>(sm + H0O + r1 * 64);
#pragma unroll
            for (int k4 = 0; k4 < 16; ++k4) {
                const float4 w0 = *reinterpret_cast<const float4*>(sm + W1O + g0 * 68 + k4 * 4);
                const float4 w1 = *reinterpret_cast<const float4*>(sm + W1O + g1 * 68 + k4 * 4);
                const float4 hv0 = hp0[k4], hv1 = hp1[k4];
                fma4v(a00, hv0, w0); fma4v(a01, hv0, w1);
                fma4v(a10, hv1, w0); fma4v(a11, hv1, w1);
            }
        }
        pre[pw0 + g0] = a00; pre[pw0 + g1] = a01;
        pre[pw1 + g0] = a10; pre[pw1 + g1] = a11;
        __syncthreads();

        // ---- phase B: combine layer 0 (threads 0..255 own c0[rr][jj]) ----
        if (tid < 256) {
            const float* p0 = pre + rr * 256;
            const float* p1 = pre + 1024 + rr * 256;
            const float ig = sigm(p0[jj]       + p1[jj]);
            const float fg = sigm(p0[64 + jj]  + p1[64 + jj]);
            const float gg = tanh_(p0[128 + jj] + p1[128 + jj]);
            const float og = sigm(p0[192 + jj] + p1[192 + jj]);
            c_state = fmaf(fg, c_state, ig * gg);
            sm[H0O + tid] = og * tanh_(c_state);
        }
        __syncthreads();

        // ---- phase C: layer-1 partials (weights in registers) ----
        {
            const int ibase = q ? H1O : H0O;
            const float4* ip0 = reinterpret_cast<const float4*>(sm + ibase + r0 * 64);
            const float4* ip1 = reinterpret_cast<const float4*>(sm + ibase + r1 * 64);
            float b00 = i1a, b01 = i1b, b10 = i1a, b11 = i1b;
#pragma unroll
            for (int k4 = 0; k4 < 16; ++k4) {
                const float4 v0 = ip0[k4], v1 = ip1[k4];
                fma4v(b00, v0, wra[k4]); fma4v(b01, v0, wrb[k4]);
                fma4v(b10, v1, wra[k4]); fma4v(b11, v1, wrb[k4]);
            }
            pre[pw0 + g0] = b00; pre[pw0 + g1] = b01;
            pre[pw1 + g0] = b10; pre[pw1 + g1] = b11;
        }
        __syncthreads();

        // ---- phase D: combine layer 1 (threads 256..511 own c1[rr][jj]) ----
        if (tid >= 256) {
            const float* p0 = pre + rr * 256;
            const float* p1 = pre + 1024 + rr * 256;
            const float ig = sigm(p0[jj]       + p1[jj]);
            const float fg = sigm(p0[64 + jj]  + p1[64 + jj]);
            const float gg = tanh_(p0[128 + jj] + p1[128 + jj]);
            const float og = sigm(p0[192 + jj] + p1[192 + jj]);
            c_state = fmaf(fg, c_state, ig * gg);
            sm[H1O + (tid & 255)] = og * tanh_(c_state);
        }
        __syncthreads();
    }

    // ===================== decoder setup =====================
    for (int idx = tid; idx < DIM * DIM; idx += THREADS) {   // W_fc overlay on W_hh0
        const int g = idx >> 6, k = idx & 63;
        sm[W1O + g * 68 + k] = Wfc[idx];
    }
    if (tid < 256) sm[DBO + tid] = sm[H1O + tid];            // carry = h2[:, -1, :]
    __syncthreads();

    const int kh  = tid >> 8;          // FC k-half
    const int fr  = (tid & 255) >> 6;  // FC row
    const int fj  = tid & 63;          // FC output index
    const float bfc_j = sm[BFCO + fj];

    // ===================== decoder: 96 autoregressive steps =====================
    for (int p = 0; p < PRED; ++p) {
        // ---- cell0 (zero state): pre = dbuf@Wih0^T + bsum0, k split by q ----
        float a00 = i0a, a01 = i0b, a10 = i0a, a11 = i0b;
        {
            const float4* dp0 = reinterpret_cast<const float4*>(sm + DBO + r0 * 64);
            const float4* dp1 = reinterpret_cast<const float4*>(sm + DBO + r1 * 64);
            const int kb = q * 8;
#pragma unroll
            for (int k4i = 0; k4i < 8; ++k4i) {
                const int k4 = kb + k4i;
                const float4 w0 = *reinterpret_cast<const float4*>(sm + W0O + g0 * 68 + k4 * 4);
                const float4 w1 = *reinterpret_cast<const float4*>(sm + W0O + g1 * 68 + k4 * 4);
                const float4 v0 = dp0[k4], v1 = dp1[k4];
                fma4v(a00, v0, w0); fma4v(a01, v0, w1);
                fma4v(a10, v1, w0); fma4v(a11, v1, w1);
            }
        }
        pre[pw0 + g0] = a00; pre[pw0 + g1] = a01;
        pre[pw1 + g0] = a10; pre[pw1 + g1] = a11;
        __syncthreads();
        if (tid < 256) {   // zero-state combine: c = i*g, h = o*tanh(c)
            const float* p0 = pre + rr * 256;
            const float* p1 = pre + 1024 + rr * 256;
            const float ig = sigm(p0[jj]        + p1[jj]);
            const float gg = tanh_(p0[128 + jj] + p1[128 + jj]);
            const float og = sigm(p0[192 + jj]  + p1[192 + jj]);
            sm[H0O + tid] = og * tanh_(ig * gg);
        }
        __syncthreads();

        // ---- cell1 (zero state): only q==0 threads hold W_ih1 in registers ----
        if (q == 0) {
            const float4* ip0 = reinterpret_cast<const float4*>(sm + H0O + r0 * 64);
            const float4* ip1 = reinterpret_cast<const float4*>(sm + H0O + r1 * 64);
            float b00 = i1a, b01 = i1b, b10 = i1a, b11 = i1b;
#pragma unroll
            for (int k4 = 0; k4 < 16; ++k4) {
                const float4 v0 = ip0[k4], v1 = ip1[k4];
                fma4v(b00, v0, wra[k4]); fma4v(b01, v0, wrb[k4]);
                fma4v(b10, v1, wra[k4]); fma4v(b11, v1, wrb[k4]);
            }
            pre[r0 * 256 + g0] = b00; pre[r0 * 256 + g1] = b01;
            pre[r1 * 256 + g0] = b10; pre[r1 * 256 + g1] = b11;
        }
        __syncthreads();
        if (tid >= 256) {
            const float* p0 = pre + rr * 256;   // part 0 only (full sums)
            const float ig = sigm(p0[jj]);
            const float gg = tanh_(p0[128 + jj]);
            const float og = sigm(p0[192 + jj]);
            sm[H1O + (tid & 255)] = og * tanh_(ig * gg);
        }
        __syncthreads();

        // ---- FC: pred[r][j] = b_fc[j] + h1[r]·W_fc[j], k split by kh ----
        {
            float acc = kh ? 0.0f : bfc_j;
            const float4* hp = reinterpret_cast<const float4*>(sm + H1O + fr * 64 + kh * 32);
#pragma unroll
            for (int k4 = 0; k4 < 8; ++k4) {
                const float4 hv = hp[k4];
                const float4 wf = *reinterpret_cast<const float4*>(sm + W1O + fj * 68 + kh * 32 + k4 * 4);
                fma4v(acc, hv, wf);
            }
            pre[kh * 1024 + fr * 256 + fj] = acc;
        }
        __syncthreads();
        if (tid < 256) {
            const float v = pre[rr * 256 + jj] + pre[1024 + rr * 256 + jj];
            out[(size_t)(row0 + rr) * PRED * DIM + p * DIM + jj] = v;   // coalesced
            sm[DBO + tid] = v;                                          // feedback
        }
        __syncthreads();
    }
}

extern "C" void kernel_launch(void* const* d_in, const int* in_sizes, int n_in,
                              void* d_out, int out_size, void* d_ws, size_t ws_size,
                              hipStream_t stream) {
    const float* x    = (const float*)d_in[0];
    const float* Wih0 = (const float*)d_in[1];
    const float* Whh0 = (const float*)d_in[2];
    const float* bih0 = (const float*)d_in[3];
    const float* bhh0 = (const float*)d_in[4];
    const float* Wih1 = (const float*)d_in[5];
    const float* Whh1 = (const float*)d_in[6];
    const float* bih1 = (const float*)d_in[7];
    const float* bhh1 = (const float*)d_in[8];
    const float* Wfc  = (const float*)d_in[9];
    const float* bfc  = (const float*)d_in[10];
    float* out = (float*)d_out;

    (void)hipFuncSetAttribute(reinterpret_cast<const void*>(rnn_fused),
                              hipFuncAttributeMaxDynamicSharedMemorySize, SMEM_BYTES);

    hipLaunchKernelGGL(rnn_fused, dim3(NB / 4), dim3(THREADS), SMEM_BYTES, stream,
                       x, Wih0, Whh0, bih0, bhh0, Wih1, Whh1, bih1, bhh1, Wfc, bfc, out);
}

// Round 3
// 2325.236 us; speedup vs baseline: 1.1768x; 1.0137x over previous
//
#include <hip/hip_runtime.h>

#define NB    1024
#define TSEQ  336
#define DIM   64
#define GATES 256
#define PRED  96
#define THREADS 512

// LDS layout (float offsets). Weights interleaved [k4][g]·float4 so that
// consecutive lanes read CONSECUTIVE float4s (conflict-free b128 — the 272B
// lane-stride of R2 cost 6.4e8 conflict cycles).
#define W0O   0        // W_ih0: [16][256][4] = 16384 ; entry (k4,g,c) = W[g][4k4+c]
#define W1O   16384    // W_hh0: [16][256][4] ; decoder overlays W_fc [16][64][4]
#define P0O   32768    // layer-0 partials [2][4][256] = 2048
#define P1O   34816    // layer-1 partials [2][4][256] = 2048
#define H0O   36864    // [4][64]
#define H1O   37120    // [4][64]
#define DBO   37376    // [4][64] decoder feedback / encoder carry
#define BS0O  37632    // 256
#define BS1O  37888    // 256
#define BFCO  38144    // 64
#define SMF   38208
#define SMEM_BYTES (SMF * 4)

__device__ __forceinline__ float sigm(float v)  { return 1.0f / (1.0f + __expf(-v)); }
__device__ __forceinline__ float tanh_(float v) { return 1.0f - 2.0f / (__expf(2.0f * v) + 1.0f); }

__device__ __forceinline__ void fma4v(float& acc, const float4 xv, const float4 w) {
    acc = fmaf(xv.x, w.x, acc); acc = fmaf(xv.y, w.y, acc);
    acc = fmaf(xv.z, w.z, acc); acc = fmaf(xv.w, w.w, acc);
}

extern "C" __global__ void __launch_bounds__(THREADS, 2)
rnn_fused(const float* __restrict__ x,
          const float* __restrict__ Wih0, const float* __restrict__ Whh0,
          const float* __restrict__ bih0, const float* __restrict__ bhh0,
          const float* __restrict__ Wih1, const float* __restrict__ Whh1,
          const float* __restrict__ bih1, const float* __restrict__ bhh1,
          const float* __restrict__ Wfc,  const float* __restrict__ bfc,
          float* __restrict__ out)
{
    extern __shared__ float sm[];
    const int tid = threadIdx.x;
    const int bid = blockIdx.x;
    const int grp = tid >> 7;          // 0..3, wave-uniform
    const int a   = grp >> 1;          // row-pair: rows 2a, 2a+1
    const int q   = grp & 1;           // 0: ih partial, 1: hh partial
    const int gp  = tid & 127;
    const int g0  = gp, g1 = gp + 128;
    const int rr  = (tid & 255) >> 6;  // combine row
    const int jj  = tid & 63;          // combine hidden index

    // ---- stage layer-0 weights interleaved: sm[k4*1024 + g*4 + c] = W[g][4k4+c] ----
    for (int idx = tid; idx < GATES * DIM; idx += THREADS) {
        const int g = idx >> 6, k = idx & 63;
        const int dst = (k >> 2) * 1024 + g * 4 + (k & 3);
        sm[W0O + dst] = Wih0[idx];
        sm[W1O + dst] = Whh0[idx];
    }
    if (tid < GATES) {
        sm[BS0O + tid] = bih0[tid] + bhh0[tid];
        sm[BS1O + tid] = bih1[tid] + bhh1[tid];
    }
    if (tid < DIM) sm[BFCO + tid] = bfc[tid];
    if (tid < 256) { sm[H0O + tid] = 0.0f; sm[H1O + tid] = 0.0f; }

    // ---- layer-1 weights in registers: rows g0,g1 of (q ? W_hh1 : W_ih1) ----
    const float* Wsrc1 = q ? Whh1 : Wih1;
    float4 wra[16], wrb[16];
#pragma unroll
    for (int k4 = 0; k4 < 16; ++k4) {
        wra[k4] = *reinterpret_cast<const float4*>(Wsrc1 + g0 * DIM + k4 * 4);
        wrb[k4] = *reinterpret_cast<const float4*>(Wsrc1 + g1 * DIM + k4 * 4);
    }
    __syncthreads();

    const float i0a = q ? 0.0f : sm[BS0O + g0];
    const float i0b = q ? 0.0f : sm[BS0O + g1];
    const float i1a = q ? 0.0f : sm[BS1O + g0];
    const float i1b = q ? 0.0f : sm[BS1O + g1];

    const int row0 = bid * 4;
    const int r0 = 2 * a, r1 = 2 * a + 1;
    const float* xr0 = x + (size_t)(row0 + r0) * TSEQ * DIM;
    const float* xr1 = x + (size_t)(row0 + r1) * TSEQ * DIM;

    const int pw0 = q * 1024 + r0 * 256;
    const int pw1 = q * 1024 + r1 * 256;

    float c_state = 0.0f;   // c0 for tid<256 at (rr,jj); c1 for tid>=256

    // ============ encoder: 336 steps, 3 barriers each (D_{s-1} overlaps A_s) ============
    for (int s = 0; s < TSEQ; ++s) {
        // ---- seg1: A_s (all threads) + D_{s-1} (tid>=256) ----
        float a00 = i0a, a01 = i0b, a10 = i0a, a11 = i0b;
        if (q == 0) {
            const float4* xp0 = reinterpret_cast<const float4*>(xr0 + s * DIM);
            const float4* xp1 = reinterpret_cast<const float4*>(xr1 + s * DIM);
#pragma unroll
            for (int k4 = 0; k4 < 16; ++k4) {
                const float4 w0 = *reinterpret_cast<const float4*>(sm + W0O + k4 * 1024 + g0 * 4);
                const float4 w1 = *reinterpret_cast<const float4*>(sm + W0O + k4 * 1024 + g1 * 4);
                const float4 xv0 = xp0[k4], xv1 = xp1[k4];
                fma4v(a00, xv0, w0); fma4v(a01, xv0, w1);
                fma4v(a10, xv1, w0); fma4v(a11, xv1, w1);
            }
        } else {
            const float4* hp0 = reinterpret_cast<const float4*>(sm + H0O + r0 * 64);
            const float4* hp1 = reinterpret_cast<const float4*>(sm + H0O + r1 * 64);
#pragma unroll
            for (int k4 = 0; k4 < 16; ++k4) {
                const float4 w0 = *reinterpret_cast<const float4*>(sm + W1O + k4 * 1024 + g0 * 4);
                const float4 w1 = *reinterpret_cast<const float4*>(sm + W1O + k4 * 1024 + g1 * 4);
                const float4 hv0 = hp0[k4], hv1 = hp1[k4];
                fma4v(a00, hv0, w0); fma4v(a01, hv0, w1);
                fma4v(a10, hv1, w0); fma4v(a11, hv1, w1);
            }
        }
        sm[P0O + pw0 + g0] = a00; sm[P0O + pw0 + g1] = a01;
        sm[P0O + pw1 + g0] = a10; sm[P0O + pw1 + g1] = a11;
        if (s != 0 && tid >= 256) {      // D_{s-1}: combine layer 1
            const float* p0 = sm + P1O + rr * 256;
            const float* p1 = sm + P1O + 1024 + rr * 256;
            const float ig = sigm(p0[jj]        + p1[jj]);
            const float fg = sigm(p0[64 + jj]   + p1[64 + jj]);
            const float gg = tanh_(p0[128 + jj] + p1[128 + jj]);
            const float og = sigm(p0[192 + jj]  + p1[192 + jj]);
            c_state = fmaf(fg, c_state, ig * gg);
            sm[H1O + (tid & 255)] = og * tanh_(c_state);
        }
        __syncthreads();

        // ---- seg2: B_s combine layer 0 (tid<256) ----
        if (tid < 256) {
            const float* p0 = sm + P0O + rr * 256;
            const float* p1 = sm + P0O + 1024 + rr * 256;
            const float ig = sigm(p0[jj]        + p1[jj]);
            const float fg = sigm(p0[64 + jj]   + p1[64 + jj]);
            const float gg = tanh_(p0[128 + jj] + p1[128 + jj]);
            const float og = sigm(p0[192 + jj]  + p1[192 + jj]);
            c_state = fmaf(fg, c_state, ig * gg);
            sm[H0O + tid] = og * tanh_(c_state);
        }
        __syncthreads();

        // ---- seg3: C_s layer-1 partials (register weights) ----
        {
            const int ibase = q ? H1O : H0O;
            const float4* ip0 = reinterpret_cast<const float4*>(sm + ibase + r0 * 64);
            const float4* ip1 = reinterpret_cast<const float4*>(sm + ibase + r1 * 64);
            float b00 = i1a, b01 = i1b, b10 = i1a, b11 = i1b;
#pragma unroll
            for (int k4 = 0; k4 < 16; ++k4) {
                const float4 v0 = ip0[k4], v1 = ip1[k4];
                fma4v(b00, v0, wra[k4]); fma4v(b01, v0, wrb[k4]);
                fma4v(b10, v1, wra[k4]); fma4v(b11, v1, wrb[k4]);
            }
            sm[P1O + pw0 + g0] = b00; sm[P1O + pw0 + g1] = b01;
            sm[P1O + pw1 + g0] = b10; sm[P1O + pw1 + g1] = b11;
        }
        __syncthreads();
    }

    // ---- final D_335 -> decoder carry (DBO) + W_fc overlay, one barrier ----
    if (tid >= 256) {
        const float* p0 = sm + P1O + rr * 256;
        const float* p1 = sm + P1O + 1024 + rr * 256;
        const float ig = sigm(p0[jj]        + p1[jj]);
        const float fg = sigm(p0[64 + jj]   + p1[64 + jj]);
        const float gg = tanh_(p0[128 + jj] + p1[128 + jj]);
        const float og = sigm(p0[192 + jj]  + p1[192 + jj]);
        c_state = fmaf(fg, c_state, ig * gg);
        sm[DBO + (tid & 255)] = og * tanh_(c_state);
    }
    for (int idx = tid; idx < DIM * DIM; idx += THREADS) {   // W_fc overlay on W_hh0
        const int j = idx >> 6, k = idx & 63;
        sm[W1O + (k >> 2) * 256 + j * 4 + (k & 3)] = Wfc[idx];
    }
    __syncthreads();

    const float bfc_j = sm[BFCO + jj];

    // ============ decoder: 96 autoregressive steps, 5 barriers each ============
    for (int p = 0; p < PRED; ++p) {
        // ---- seg1: cell0 matvec (all threads, k-split by q) ----
        {
            const float4* dp0 = reinterpret_cast<const float4*>(sm + DBO + r0 * 64);
            const float4* dp1 = reinterpret_cast<const float4*>(sm + DBO + r1 * 64);
            float a00 = i0a, a01 = i0b, a10 = i0a, a11 = i0b;
            const int kb = q * 8;
#pragma unroll
            for (int k4i = 0; k4i < 8; ++k4i) {
                const int k4 = kb + k4i;
                const float4 w0 = *reinterpret_cast<const float4*>(sm + W0O + k4 * 1024 + g0 * 4);
                const float4 w1 = *reinterpret_cast<const float4*>(sm + W0O + k4 * 1024 + g1 * 4);
                const float4 v0 = dp0[k4], v1 = dp1[k4];
                fma4v(a00, v0, w0); fma4v(a01, v0, w1);
                fma4v(a10, v1, w0); fma4v(a11, v1, w1);
            }
            sm[P0O + pw0 + g0] = a00; sm[P0O + pw0 + g1] = a01;
            sm[P0O + pw1 + g0] = a10; sm[P0O + pw1 + g1] = a11;
        }
        __syncthreads();

        // ---- seg2: combine0 (tid<256), zero state: c=i*g ----
        if (tid < 256) {
            const float* p0 = sm + P0O + rr * 256;
            const float* p1 = sm + P0O + 1024 + rr * 256;
            const float ig = sigm(p0[jj]        + p1[jj]);
            const float gg = tanh_(p0[128 + jj] + p1[128 + jj]);
            const float og = sigm(p0[192 + jj]  + p1[192 + jj]);
            sm[H0O + tid] = og * tanh_(ig * gg);
        }
        __syncthreads();

        // ---- seg3: cell1 matvec (q==0 threads, W_ih1 registers) ----
        if (q == 0) {
            const float4* ip0 = reinterpret_cast<const float4*>(sm + H0O + r0 * 64);
            const float4* ip1 = reinterpret_cast<const float4*>(sm + H0O + r1 * 64);
            float b00 = i1a, b01 = i1b, b10 = i1a, b11 = i1b;
#pragma unroll
            for (int k4 = 0; k4 < 16; ++k4) {
                const float4 v0 = ip0[k4], v1 = ip1[k4];
                fma4v(b00, v0, wra[k4]); fma4v(b01, v0, wrb[k4]);
                fma4v(b10, v1, wra[k4]); fma4v(b11, v1, wrb[k4]);
            }
            sm[P1O + r0 * 256 + g0] = b00; sm[P1O + r0 * 256 + g1] = b01;
            sm[P1O + r1 * 256 + g0] = b10; sm[P1O + r1 * 256 + g1] = b11;
        }
        __syncthreads();

        // ---- seg4: combine1 (tid>=256), zero state ----
        if (tid >= 256) {
            const float* p0 = sm + P1O + rr * 256;
            const float ig = sigm(p0[jj]);
            const float gg = tanh_(p0[128 + jj]);
            const float og = sigm(p0[192 + jj]);
            sm[H1O + (tid & 255)] = og * tanh_(ig * gg);
        }
        __syncthreads();

        // ---- seg5: FC full dot (tid<256) + out + feedback ----
        if (tid < 256) {
            float acc = bfc_j;
            const float4* hp = reinterpret_cast<const float4*>(sm + H1O + rr * 64);
#pragma unroll
            for (int k4 = 0; k4 < 16; ++k4) {
                const float4 hv = hp[k4];
                const float4 wf = *reinterpret_cast<const float4*>(sm + W1O + k4 * 256 + jj * 4);
                fma4v(acc, hv, wf);
            }
            out[(size_t)(row0 + rr) * PRED * DIM + p * DIM + jj] = acc;
            sm[DBO + tid] = acc;
        }
        __syncthreads();
    }
}

extern "C" void kernel_launch(void* const* d_in, const int* in_sizes, int n_in,
                              void* d_out, int out_size, void* d_ws, size_t ws_size,
                              hipStream_t stream) {
    const float* x    = (const float*)d_in[0];
    const float* Wih0 = (const float*)d_in[1];
    const float* Whh0 = (const float*)d_in[2];
    const float* bih0 = (const float*)d_in[3];
    const float* bhh0 = (const float*)d_in[4];
    const float* Wih1 = (const float*)d_in[5];
    const float* Whh1 = (const float*)d_in[6];
    const float* bih1 = (const float*)d_in[7];
    const float* bhh1 = (const float*)d_in[8];
    const float* Wfc  = (const float*)d_in[9];
    const float* bfc  = (const float*)d_in[10];
    float* out = (float*)d_out;

    (void)hipFuncSetAttribute(reinterpret_cast<const void*>(rnn_fused),
                              hipFuncAttributeMaxDynamicSharedMemorySize, SMEM_BYTES);

    hipLaunchKernelGGL(rnn_fused, dim3(NB / 4), dim3(THREADS), SMEM_BYTES, stream,
                       x, Wih0, Whh0, bih0, bhh0, Wih1, Whh1, bih1, bhh1, Wfc, bfc, out);
}

// Round 4
// 1809.834 us; speedup vs baseline: 1.5119x; 1.2848x over previous
//
#include <hip/hip_runtime.h>

#define NB    1024
#define TSEQ  336
#define DIM   64
#define GATES 256
#define PRED  96
#define THREADS 512

// LDS layout (float offsets). NO weight matrices in LDS (all in VGPRs) —
// R2/R3 showed per-lane ds_read_b128 is inherently ~8-way conflicted on
// gfx950 (6.4e8 conflict cycles, layout-independent). Remaining LDS traffic
// is stride-1 b32 (2-way, free) and wave-uniform b128 broadcasts (free, R1).
#define P0O   0        // layer-0 partials [4 copies][4 rows][256 gates]
#define P1O   4096     // layer-1 partials [4][4][256]
#define WFCO  8192     // W_fc [16][4][64] : (k4,c,j) = W[j][4k4+c]
#define H0O   12288    // [4][64]
#define H1O   12544    // [4][64]
#define DBO   12800    // [4][64] decoder feedback
#define BS0O  13056    // 256
#define BS1O  13312    // 256
#define BFCO  13568    // 64
#define SMF   13632
#define SMEM_BYTES (SMF * 4)

__device__ __forceinline__ float sigm(float v)  { return 1.0f / (1.0f + __expf(-v)); }
__device__ __forceinline__ float tanh_(float v) { return 1.0f - 2.0f / (__expf(2.0f * v) + 1.0f); }

__device__ __forceinline__ void fma4v(float& acc, const float4 xv, const float4 w) {
    acc = fmaf(xv.x, w.x, acc); acc = fmaf(xv.y, w.y, acc);
    acc = fmaf(xv.z, w.z, acc); acc = fmaf(xv.w, w.w, acc);
}

extern "C" __global__ void __launch_bounds__(THREADS, 2)
rnn_fused(const float* __restrict__ x,
          const float* __restrict__ Wih0, const float* __restrict__ Whh0,
          const float* __restrict__ bih0, const float* __restrict__ bhh0,
          const float* __restrict__ Wih1, const float* __restrict__ Whh1,
          const float* __restrict__ bih1, const float* __restrict__ bhh1,
          const float* __restrict__ Wfc,  const float* __restrict__ bfc,
          float* __restrict__ out)
{
    extern __shared__ float sm[];
    const int tid = threadIdx.x;
    const int bid = blockIdx.x;
    const int grp = tid >> 7;          // 0..3 (wave-uniform): copy index
    const int m   = grp & 1;           // 0: ih matrix, 1: hh matrix
    const int kh  = grp >> 1;          // k-half: k in [kh*32, kh*32+32)
    const int gp  = tid & 127;
    const int g0  = gp, g1 = gp + 128; // owned gate rows
    const int rr  = (tid & 255) >> 6;  // combine row
    const int jj  = tid & 63;          // combine hidden index

    // ---- prologue staging (biases, W_fc, zero states) ----
    if (tid < GATES) {
        sm[BS0O + tid] = bih0[tid] + bhh0[tid];
        sm[BS1O + tid] = bih1[tid] + bhh1[tid];
    }
    if (tid < DIM) sm[BFCO + tid] = bfc[tid];
    if (tid < 256) { sm[H0O + tid] = 0.0f; sm[H1O + tid] = 0.0f; }
    for (int idx = tid; idx < DIM * DIM; idx += THREADS) {   // W_fc: (k4,c,j)
        const int j = idx >> 6, k = idx & 63;
        sm[WFCO + (k >> 2) * 256 + (k & 3) * 64 + j] = Wfc[idx];
    }

    // ---- ALL recurrent weights in registers: 32 float4 = 128 VGPR/thread ----
    const float* Wsrc0 = m ? Whh0 : Wih0;
    const float* Wsrc1 = m ? Whh1 : Wih1;
    float4 w0a[8], w0b[8], w1a[8], w1b[8];
#pragma unroll
    for (int k4 = 0; k4 < 8; ++k4) {
        w0a[k4] = *reinterpret_cast<const float4*>(Wsrc0 + g0 * DIM + kh * 32 + k4 * 4);
        w0b[k4] = *reinterpret_cast<const float4*>(Wsrc0 + g1 * DIM + kh * 32 + k4 * 4);
        w1a[k4] = *reinterpret_cast<const float4*>(Wsrc1 + g0 * DIM + kh * 32 + k4 * 4);
        w1b[k4] = *reinterpret_cast<const float4*>(Wsrc1 + g1 * DIM + kh * 32 + k4 * 4);
    }
    __syncthreads();

    const int row0 = bid * 4;
    const float* xr0 = x + (size_t)(row0 + 0) * TSEQ * DIM + kh * 32;
    const float* xr1 = x + (size_t)(row0 + 1) * TSEQ * DIM + kh * 32;
    const float* xr2 = x + (size_t)(row0 + 2) * TSEQ * DIM + kh * 32;
    const float* xr3 = x + (size_t)(row0 + 3) * TSEQ * DIM + kh * 32;

    const int pb = grp * 1024;         // this group's partial-copy base
    float c_state = 0.0f;              // c0 for tid<256 at (rr,jj); c1 for tid>=256

    // ============ encoder: 336 steps, 3 barriers (combine1_{s-1} overlaps seg1) ============
    for (int s = 0; s < TSEQ; ++s) {
        // ---- seg1: combine1(s-1) on tid>=256, + layer-0 matvec on all ----
        if (s != 0 && tid >= 256) {
            float pi = sm[BS1O + jj],       pf = sm[BS1O + 64 + jj];
            float pg = sm[BS1O + 128 + jj], po = sm[BS1O + 192 + jj];
#pragma unroll
            for (int cp = 0; cp < 4; ++cp) {
                const float* p = sm + P1O + cp * 1024 + rr * 256;
                pi += p[jj]; pf += p[64 + jj]; pg += p[128 + jj]; po += p[192 + jj];
            }
            const float ig = sigm(pi), fg = sigm(pf), gg = tanh_(pg), og = sigm(po);
            c_state = fmaf(fg, c_state, ig * gg);
            sm[H1O + (tid & 255)] = og * tanh_(c_state);
        }
        {
            float acc[8];
#pragma unroll
            for (int i = 0; i < 8; ++i) acc[i] = 0.0f;
            if (m == 0) {        // x-part: wave-uniform GLOBAL loads (VMEM pipe)
                const int so = s * DIM;
#pragma unroll
                for (int k4 = 0; k4 < 8; ++k4) {
                    const float4 v0 = *reinterpret_cast<const float4*>(xr0 + so + k4 * 4);
                    const float4 v1 = *reinterpret_cast<const float4*>(xr1 + so + k4 * 4);
                    const float4 v2 = *reinterpret_cast<const float4*>(xr2 + so + k4 * 4);
                    const float4 v3 = *reinterpret_cast<const float4*>(xr3 + so + k4 * 4);
                    fma4v(acc[0], v0, w0a[k4]); fma4v(acc[1], v0, w0b[k4]);
                    fma4v(acc[2], v1, w0a[k4]); fma4v(acc[3], v1, w0b[k4]);
                    fma4v(acc[4], v2, w0a[k4]); fma4v(acc[5], v2, w0b[k4]);
                    fma4v(acc[6], v3, w0a[k4]); fma4v(acc[7], v3, w0b[k4]);
                }
            } else {             // h-part: wave-uniform LDS b128 broadcasts (free)
#pragma unroll
                for (int k4 = 0; k4 < 8; ++k4) {
                    const float4 v0 = *reinterpret_cast<const float4*>(sm + H0O + 0 * 64 + kh * 32 + k4 * 4);
                    const float4 v1 = *reinterpret_cast<const float4*>(sm + H0O + 1 * 64 + kh * 32 + k4 * 4);
                    const float4 v2 = *reinterpret_cast<const float4*>(sm + H0O + 2 * 64 + kh * 32 + k4 * 4);
                    const float4 v3 = *reinterpret_cast<const float4*>(sm + H0O + 3 * 64 + kh * 32 + k4 * 4);
                    fma4v(acc[0], v0, w0a[k4]); fma4v(acc[1], v0, w0b[k4]);
                    fma4v(acc[2], v1, w0a[k4]); fma4v(acc[3], v1, w0b[k4]);
                    fma4v(acc[4], v2, w0a[k4]); fma4v(acc[5], v2, w0b[k4]);
                    fma4v(acc[6], v3, w0a[k4]); fma4v(acc[7], v3, w0b[k4]);
                }
            }
            sm[P0O + pb + 0 * 256 + g0] = acc[0]; sm[P0O + pb + 0 * 256 + g1] = acc[1];
            sm[P0O + pb + 1 * 256 + g0] = acc[2]; sm[P0O + pb + 1 * 256 + g1] = acc[3];
            sm[P0O + pb + 2 * 256 + g0] = acc[4]; sm[P0O + pb + 2 * 256 + g1] = acc[5];
            sm[P0O + pb + 3 * 256 + g0] = acc[6]; sm[P0O + pb + 3 * 256 + g1] = acc[7];
        }
        __syncthreads();

        // ---- seg2: combine0 (tid<256) ----
        if (tid < 256) {
            float pi = sm[BS0O + jj],       pf = sm[BS0O + 64 + jj];
            float pg = sm[BS0O + 128 + jj], po = sm[BS0O + 192 + jj];
#pragma unroll
            for (int cp = 0; cp < 4; ++cp) {
                const float* p = sm + P0O + cp * 1024 + rr * 256;
                pi += p[jj]; pf += p[64 + jj]; pg += p[128 + jj]; po += p[192 + jj];
            }
            const float ig = sigm(pi), fg = sigm(pf), gg = tanh_(pg), og = sigm(po);
            c_state = fmaf(fg, c_state, ig * gg);
            sm[H0O + tid] = og * tanh_(c_state);
        }
        __syncthreads();

        // ---- seg3: layer-1 matvec (register weights; m selects h0_s / h1_{s-1}) ----
        {
            const int ib = m ? H1O : H0O;
            float acc[8];
#pragma unroll
            for (int i = 0; i < 8; ++i) acc[i] = 0.0f;
#pragma unroll
            for (int k4 = 0; k4 < 8; ++k4) {
                const float4 v0 = *reinterpret_cast<const float4*>(sm + ib + 0 * 64 + kh * 32 + k4 * 4);
                const float4 v1 = *reinterpret_cast<const float4*>(sm + ib + 1 * 64 + kh * 32 + k4 * 4);
                const float4 v2 = *reinterpret_cast<const float4*>(sm + ib + 2 * 64 + kh * 32 + k4 * 4);
                const float4 v3 = *reinterpret_cast<const float4*>(sm + ib + 3 * 64 + kh * 32 + k4 * 4);
                fma4v(acc[0], v0, w1a[k4]); fma4v(acc[1], v0, w1b[k4]);
                fma4v(acc[2], v1, w1a[k4]); fma4v(acc[3], v1, w1b[k4]);
                fma4v(acc[4], v2, w1a[k4]); fma4v(acc[5], v2, w1b[k4]);
                fma4v(acc[6], v3, w1a[k4]); fma4v(acc[7], v3, w1b[k4]);
            }
            sm[P1O + pb + 0 * 256 + g0] = acc[0]; sm[P1O + pb + 0 * 256 + g1] = acc[1];
            sm[P1O + pb + 1 * 256 + g0] = acc[2]; sm[P1O + pb + 1 * 256 + g1] = acc[3];
            sm[P1O + pb + 2 * 256 + g0] = acc[4]; sm[P1O + pb + 2 * 256 + g1] = acc[5];
            sm[P1O + pb + 3 * 256 + g0] = acc[6]; sm[P1O + pb + 3 * 256 + g1] = acc[7];
        }
        __syncthreads();
    }

    // ---- final combine1 (s=335) -> decoder carry ----
    if (tid >= 256) {
        float pi = sm[BS1O + jj],       pf = sm[BS1O + 64 + jj];
        float pg = sm[BS1O + 128 + jj], po = sm[BS1O + 192 + jj];
#pragma unroll
        for (int cp = 0; cp < 4; ++cp) {
            const float* p = sm + P1O + cp * 1024 + rr * 256;
            pi += p[jj]; pf += p[64 + jj]; pg += p[128 + jj]; po += p[192 + jj];
        }
        const float ig = sigm(pi), fg = sigm(pf), gg = tanh_(pg), og = sigm(po);
        c_state = fmaf(fg, c_state, ig * gg);
        sm[DBO + (tid & 255)] = og * tanh_(c_state);
    }
    __syncthreads();

    const float bfc_j = sm[BFCO + jj];

    // ============ decoder: 96 autoregressive steps (zero-state cells) ============
    for (int p = 0; p < PRED; ++p) {
        // ---- seg1: cell0 = db@Wih0^T (m==0 groups; copies 0 and 2) ----
        if (m == 0) {
            float acc[8];
#pragma unroll
            for (int i = 0; i < 8; ++i) acc[i] = 0.0f;
#pragma unroll
            for (int k4 = 0; k4 < 8; ++k4) {
                const float4 v0 = *reinterpret_cast<const float4*>(sm + DBO + 0 * 64 + kh * 32 + k4 * 4);
                const float4 v1 = *reinterpret_cast<const float4*>(sm + DBO + 1 * 64 + kh * 32 + k4 * 4);
                const float4 v2 = *reinterpret_cast<const float4*>(sm + DBO + 2 * 64 + kh * 32 + k4 * 4);
                const float4 v3 = *reinterpret_cast<const float4*>(sm + DBO + 3 * 64 + kh * 32 + k4 * 4);
                fma4v(acc[0], v0, w0a[k4]); fma4v(acc[1], v0, w0b[k4]);
                fma4v(acc[2], v1, w0a[k4]); fma4v(acc[3], v1, w0b[k4]);
                fma4v(acc[4], v2, w0a[k4]); fma4v(acc[5], v2, w0b[k4]);
                fma4v(acc[6], v3, w0a[k4]); fma4v(acc[7], v3, w0b[k4]);
            }
            sm[P0O + pb + 0 * 256 + g0] = acc[0]; sm[P0O + pb + 0 * 256 + g1] = acc[1];
            sm[P0O + pb + 1 * 256 + g0] = acc[2]; sm[P0O + pb + 1 * 256 + g1] = acc[3];
            sm[P0O + pb + 2 * 256 + g0] = acc[4]; sm[P0O + pb + 2 * 256 + g1] = acc[5];
            sm[P0O + pb + 3 * 256 + g0] = acc[6]; sm[P0O + pb + 3 * 256 + g1] = acc[7];
        }
        __syncthreads();
        if (tid < 256) {   // combine0 zero-state: c=i*g
            float pi = sm[BS0O + jj], pg = sm[BS0O + 128 + jj], po = sm[BS0O + 192 + jj];
            {
                const float* pA = sm + P0O + 0 * 1024 + rr * 256;
                const float* pB = sm + P0O + 2 * 1024 + rr * 256;
                pi += pA[jj] + pB[jj];
                pg += pA[128 + jj] + pB[128 + jj];
                po += pA[192 + jj] + pB[192 + jj];
            }
            const float ig = sigm(pi), gg = tanh_(pg), og = sigm(po);
            sm[H0O + tid] = og * tanh_(ig * gg);
        }
        __syncthreads();

        // ---- seg3: cell1 = h0@Wih1^T (m==0 groups) ----
        if (m == 0) {
            float acc[8];
#pragma unroll
            for (int i = 0; i < 8; ++i) acc[i] = 0.0f;
#pragma unroll
            for (int k4 = 0; k4 < 8; ++k4) {
                const float4 v0 = *reinterpret_cast<const float4*>(sm + H0O + 0 * 64 + kh * 32 + k4 * 4);
                const float4 v1 = *reinterpret_cast<const float4*>(sm + H0O + 1 * 64 + kh * 32 + k4 * 4);
                const float4 v2 = *reinterpret_cast<const float4*>(sm + H0O + 2 * 64 + kh * 32 + k4 * 4);
                const float4 v3 = *reinterpret_cast<const float4*>(sm + H0O + 3 * 64 + kh * 32 + k4 * 4);
                fma4v(acc[0], v0, w1a[k4]); fma4v(acc[1], v0, w1b[k4]);
                fma4v(acc[2], v1, w1a[k4]); fma4v(acc[3], v1, w1b[k4]);
                fma4v(acc[4], v2, w1a[k4]); fma4v(acc[5], v2, w1b[k4]);
                fma4v(acc[6], v3, w1a[k4]); fma4v(acc[7], v3, w1b[k4]);
            }
            sm[P1O + pb + 0 * 256 + g0] = acc[0]; sm[P1O + pb + 0 * 256 + g1] = acc[1];
            sm[P1O + pb + 1 * 256 + g0] = acc[2]; sm[P1O + pb + 1 * 256 + g1] = acc[3];
            sm[P1O + pb + 2 * 256 + g0] = acc[4]; sm[P1O + pb + 2 * 256 + g1] = acc[5];
            sm[P1O + pb + 3 * 256 + g0] = acc[6]; sm[P1O + pb + 3 * 256 + g1] = acc[7];
        }
        __syncthreads();
        if (tid >= 256) {  // combine1 zero-state
            float pi = sm[BS1O + jj], pg = sm[BS1O + 128 + jj], po = sm[BS1O + 192 + jj];
            {
                const float* pA = sm + P1O + 0 * 1024 + rr * 256;
                const float* pB = sm + P1O + 2 * 1024 + rr * 256;
                pi += pA[jj] + pB[jj];
                pg += pA[128 + jj] + pB[128 + jj];
                po += pA[192 + jj] + pB[192 + jj];
            }
            const float ig = sigm(pi), gg = tanh_(pg), og = sigm(po);
            sm[H1O + (tid & 255)] = og * tanh_(ig * gg);
        }
        __syncthreads();

        // ---- seg5: FC (tid<256): stride-1 b32 W_fc reads + uniform h1 b128 ----
        if (tid < 256) {
            float acc = bfc_j;
            const float4* hp = reinterpret_cast<const float4*>(sm + H1O + rr * 64);
#pragma unroll
            for (int k4 = 0; k4 < 16; ++k4) {
                const float4 hv = hp[k4];
                const float* wp = sm + WFCO + k4 * 256;
                acc = fmaf(hv.x, wp[jj],       acc);
                acc = fmaf(hv.y, wp[64 + jj],  acc);
                acc = fmaf(hv.z, wp[128 + jj], acc);
                acc = fmaf(hv.w, wp[192 + jj], acc);
            }
            out[(size_t)(row0 + rr) * PRED * DIM + p * DIM + jj] = acc;
            sm[DBO + tid] = acc;
        }
        __syncthreads();
    }
}

extern "C" void kernel_launch(void* const* d_in, const int* in_sizes, int n_in,
                              void* d_out, int out_size, void* d_ws, size_t ws_size,
                              hipStream_t stream) {
    const float* x    = (const float*)d_in[0];
    const float* Wih0 = (const float*)d_in[1];
    const float* Whh0 = (const float*)d_in[2];
    const float* bih0 = (const float*)d_in[3];
    const float* bhh0 = (const float*)d_in[4];
    const float* Wih1 = (const float*)d_in[5];
    const float* Whh1 = (const float*)d_in[6];
    const float* bih1 = (const float*)d_in[7];
    const float* bhh1 = (const float*)d_in[8];
    const float* Wfc  = (const float*)d_in[9];
    const float* bfc  = (const float*)d_in[10];
    float* out = (float*)d_out;

    hipLaunchKernelGGL(rnn_fused, dim3(NB / 4), dim3(THREADS), SMEM_BYTES, stream,
                       x, Wih0, Whh0, bih0, bhh0, Wih1, Whh1, bih1, bhh1, Wfc, bfc, out);
}